// Round 6
// baseline (2914.308 us; speedup 1.0000x reference)
//
#include <hip/hip_runtime.h>
#include <math.h>

#define B_ 8192
#define T_ 30
#define H_ 256
#define NG_ 1024
#define DT_ 0.03f
#define RB 32
#define NBLK (B_ / RB)   // 256

typedef __attribute__((ext_vector_type(8))) short short8;
typedef __attribute__((ext_vector_type(4))) float f32x4;

__device__ inline float bf2f(unsigned short u) {
    unsigned int x = ((unsigned int)u) << 16;
    return __builtin_bit_cast(float, x);
}
__device__ inline unsigned short f2bf(float f) {
    unsigned int x = __builtin_bit_cast(unsigned int, f);
    return (unsigned short)((x + 0x7FFF + ((x >> 16) & 1)) >> 16);
}
__device__ inline float fast_tanh(float x) {
    float e = __expf(2.f * x);
    return 1.f - 2.f / (e + 1.f);
}
__device__ inline float fast_sigmoid(float x) {
    return 1.f / (1.f + __expf(-x));
}
__device__ inline void gl16(const unsigned short* g, unsigned short* l) {
    __builtin_amdgcn_global_load_lds((const __attribute__((address_space(1))) void*)g,
                                     (__attribute__((address_space(3))) void*)l, 16, 0, 0);
}

// ---------- fused fold+permute: WxP[r][n'] = (W1@W2)[r][co(n')], bfP[n'] = (b1@W2+bih+bhh)[co] ----------
// n' = bN*64 + g*16 + j  <->  co = g*256 + bN*16 + j
__global__ void fold_perm_kernel(const float* __restrict__ W1, const float* __restrict__ b1,
                                 const float* __restrict__ W2,
                                 const float* __restrict__ bih, const float* __restrict__ bhh,
                                 float* __restrict__ WxP, float* __restrict__ bfP) {
    __shared__ float sP[4][64];
    const int t63 = threadIdx.x & 63;
    const int kc = threadIdx.x >> 6;
    int o = blockIdx.x * 64 + t63;          // 0..5119 (r=4 is bias row)
    int r = o >> 10;
    int np = o & 1023;
    int bN = np >> 6, g = (np >> 4) & 3, j = np & 15;
    int co = g * 256 + bN * 16 + j;
    const float* w1row = (r < 4) ? (W1 + r * 128) : b1;
    float acc = 0.f;
    #pragma unroll 8
    for (int k = kc * 32; k < kc * 32 + 32; ++k)
        acc = fmaf(w1row[k], W2[k * NG_ + co], acc);
    sP[kc][t63] = acc;
    __syncthreads();
    if (kc == 0) {
        acc = sP[0][t63] + sP[1][t63] + sP[2][t63] + sP[3][t63];
        if (r < 4) WxP[r * NG_ + np] = acc;
        else       bfP[np] = acc + bih[co] + bhh[co];
    }
}

// WhP: permuted + BANK-SWIZZLE BAKED IN (R4-verified). Element (gate-col np, k) at
// np*256 + ((k>>3)^(np&7))*8 + (k&7), so a LINEAR global->LDS copy yields the swizzled tile.
__global__ void prep_whp_kernel(const float* __restrict__ W, unsigned short* __restrict__ WhP) {
    int id = blockIdx.x * blockDim.x + threadIdx.x;  // 1024*256
    int np = id >> 8, k = id & 255;
    int bN = np >> 6, g = (np >> 4) & 3, j = np & 15;
    int co = g * 256 + bN * 16 + j;
    int dst = np * 256 + ((((k >> 3) ^ (np & 7))) << 3) + (k & 7);
    WhP[dst] = f2bf(W[(size_t)k * NG_ + co]);
}

// WT[m][n][k] = bf16(W_m[k][n]) for 9 matrices (mu0..3, lv0..3, dec_init)
__global__ void prep_wt_all_kernel(const float* __restrict__ muW, const float* __restrict__ lvW,
                                   const float* __restrict__ diW, unsigned short* __restrict__ WT9) {
    int m = blockIdx.y;
    const float* src = (m < 4) ? muW + (size_t)m * 65536
                     : (m < 8) ? lvW + (size_t)(m - 4) * 65536
                               : diW;
    int id = blockIdx.x * 256 + threadIdx.x;
    int n = id >> 8, k = id & 255;
    WT9[(size_t)m * 65536 + id] = f2bf(src[k * H_ + n]);
}

// ---------- rel input + expert passthrough ----------
__global__ void rel_kernel(const float* __restrict__ traj, float* __restrict__ rel,
                           float4* __restrict__ expert) {
    int id = blockIdx.x * blockDim.x + threadIdx.x;
    if (id >= B_ * T_) return;
    int t = id % T_;
    const float* p = traj + (size_t)id * 4;
    float x = p[0], y = p[1];
    if (t > 0) { x -= p[-4]; y -= p[-3]; }
    float* o = rel + (size_t)id * 4;
    o[0] = x; o[1] = y; o[2] = p[2]; o[3] = p[3];
    expert[id] = ((const float4*)traj)[id];
}

// ---------- persistent LSTM v4: 4 compute waves + 4 producer waves, dbuf gl_lds staging ----------
// LDS: buf0 0..65536 | buf1 ..131072 | hL[32][264]bf16 ..147968 | wx[4][1024]bf16 ..156160
//      bf[1024]f32 ..160256 | Wc[512]f32 ..162304 | sL[32][4]f32 ..162816 | red[32][2][2]f32 ..163328
#define SMEM4 163328

template <int DEC>
__global__ __launch_bounds__(512, 2) void lstm_persist4_kernel(
    const float* __restrict__ rel,            // enc: [B][T][4]
    const unsigned short* __restrict__ WhP,   // [1024][256] bf16 permuted+swizzled
    const float* __restrict__ WxP,            // [4][1024]
    const float* __restrict__ bfP,            // [1024]
    const float* __restrict__ cInit,          // dec: [B][256] f32
    const unsigned short* __restrict__ hInit, // dec: [B][256] bf16
    const float* __restrict__ initS,          // dec: [B][4]
    const float* __restrict__ Wc,             // dec: [256][2]
    const float* __restrict__ bc,             // dec: [2]
    unsigned short* __restrict__ hOut,        // enc: [B][256] bf16
    float* __restrict__ recons)               // dec: [B][T][4]
{
    extern __shared__ char smem[];
    unsigned short* bufA = (unsigned short*)smem;
    unsigned short* bufB = (unsigned short*)(smem + 65536);
    unsigned short* hL   = (unsigned short*)(smem + 131072);
    unsigned short* wxL  = (unsigned short*)(smem + 147968);
    float* bfL  = (float*)(smem + 156160);
    float* WcL  = (float*)(smem + 160256);
    float* sLp  = (float*)(smem + 162304);
    float* redL = (float*)(smem + 162816);

    const int tid = threadIdx.x;
    const int lane = tid & 63;
    const int fr = lane & 15;
    const int kg = lane >> 4;
    const int wid = tid >> 6;
    const bool isComp = (wid < 4);
    const int rh = wid >> 1;        // compute: row-half (16 rows)
    const int c2 = wid & 1;         // compute: bN parity within chunk
    const int prod = wid - 4;       // producer index 0..3
    const int rowBase = blockIdx.x * RB;

    // ---- prologue: LDS state ----
    #pragma unroll
    for (int w = 0; w < 2; ++w) {
        int cid = tid + w * 512;                  // 1024 groups of 8 shorts
        int row = cid >> 5, seg = cid & 31;
        if (DEC) *(short8*)(hL + row * 264 + seg * 8) =
                     *(const short8*)(hInit + (size_t)(rowBase + row) * 256 + seg * 8);
        else {
            short8 z = {0, 0, 0, 0, 0, 0, 0, 0};
            *(short8*)(hL + row * 264 + seg * 8) = z;
        }
    }
    #pragma unroll
    for (int w = 0; w < 8; ++w) wxL[tid + w * 512] = f2bf(WxP[tid + w * 512]);
    #pragma unroll
    for (int w = 0; w < 2; ++w) bfL[tid + w * 512] = bfP[tid + w * 512];
    if (DEC) {
        if (tid < 128) *(float4*)(WcL + tid * 4) = *(const float4*)(Wc + tid * 4);
        if (tid < RB)  *(float4*)(sLp + tid * 4) = *(const float4*)(initS + (size_t)(rowBase + tid) * 4);
    }
    float bc0 = 0.f, bc1 = 0.f;
    if (DEC) { bc0 = bc[0]; bc1 = bc[1]; }

    // compute-wave register state
    float cReg[32];                 // [ci][rr]
    float wcReg[16];                // dec: [ci][o]
    if (isComp) {
        #pragma unroll
        for (int ci = 0; ci < 8; ++ci) {
            int u = (2 * ci + c2) * 16 + fr;
            #pragma unroll
            for (int rr = 0; rr < 4; ++rr) {
                if (DEC) cReg[ci * 4 + rr] =
                    cInit[(size_t)(rowBase + rh * 16 + kg * 4 + rr) * 256 + u];
                else cReg[ci * 4 + rr] = 0.f;
            }
            if (DEC) {
                wcReg[ci * 2 + 0] = Wc[u * 2 + 0];
                wcReg[ci * 2 + 1] = Wc[u * 2 + 1];
            }
        }
    }
    float hC[32];

    // producer helper: DMA chunk ck (0..7) into buf (linear copy; swizzle baked in source)
    #define ISSUE(ck, bufp)                                                        \
        {                                                                          \
            const unsigned short* gsrc = WhP + (size_t)(ck) * 32768 + lane * 8;    \
            unsigned short* ldst = (bufp);                                         \
            _Pragma("unroll")                                                      \
            for (int q = 0; q < 32; ++q) gl16(gsrc + q * 512, ldst + q * 512);     \
        }

    // prologue DMA: chunks 0,1
    if (prod == 0) ISSUE(0, bufA);
    if (prod == 1) ISSUE(1, bufB);
    asm volatile("s_waitcnt lgkmcnt(0)" ::: "memory");
    __builtin_amdgcn_s_barrier();   // prologue LDS visible

    for (int t = 0; t < T_; ++t) {
        // ---- B_step: h writes of prev step + sL visible ----
        asm volatile("s_waitcnt lgkmcnt(0)" ::: "memory");
        __builtin_amdgcn_s_barrier();
        __builtin_amdgcn_sched_barrier(0);

        short8 afr[8];
        float4 xv[4];
        if (isComp) {
            #pragma unroll
            for (int k0 = 0; k0 < 8; ++k0)
                afr[k0] = *(const short8*)(hL + (rh * 16 + fr) * 264 + (k0 * 4 + kg) * 8);
            #pragma unroll
            for (int rr = 0; rr < 4; ++rr) {
                int row = rh * 16 + kg * 4 + rr;
                if (DEC) xv[rr] = *(const float4*)(sLp + row * 4);
                else     xv[rr] = *(const float4*)(rel + ((size_t)(rowBase + row) * T_ + t) * 4);
            }
            asm volatile("s_waitcnt lgkmcnt(0)" ::: "memory");
        }
        if (prod == 0) asm volatile("s_waitcnt vmcnt(0)" ::: "memory");  // chunk0 DMA done
        __builtin_amdgcn_s_barrier();   // B_afr: afr reads done, chunk0 ready
        __builtin_amdgcn_sched_barrier(0);

        #pragma unroll
        for (int ci = 0; ci < 8; ++ci) {
            unsigned short* buf = (ci & 1) ? bufB : bufA;
            f32x4 acc[4] = {f32x4{0.f,0.f,0.f,0.f}, f32x4{0.f,0.f,0.f,0.f},
                            f32x4{0.f,0.f,0.f,0.f}, f32x4{0.f,0.f,0.f,0.f}};
            if (isComp) {
                __builtin_amdgcn_s_setprio(1);
                #pragma unroll
                for (int k0 = 0; k0 < 8; ++k0) {
                    int kch = k0 * 4 + kg;
                    short8 b0, b1, b2, b3;
                    {
                        int base = c2 * 64;
                        b0 = *(const short8*)(buf + (base + 0 * 16 + fr) * 256 + ((kch ^ (fr & 7)) << 3));
                        b1 = *(const short8*)(buf + (base + 1 * 16 + fr) * 256 + ((kch ^ (fr & 7)) << 3));
                        b2 = *(const short8*)(buf + (base + 2 * 16 + fr) * 256 + ((kch ^ (fr & 7)) << 3));
                        b3 = *(const short8*)(buf + (base + 3 * 16 + fr) * 256 + ((kch ^ (fr & 7)) << 3));
                    }
                    acc[0] = __builtin_amdgcn_mfma_f32_16x16x32_bf16(afr[k0], b0, acc[0], 0, 0, 0);
                    acc[1] = __builtin_amdgcn_mfma_f32_16x16x32_bf16(afr[k0], b1, acc[1], 0, 0, 0);
                    acc[2] = __builtin_amdgcn_mfma_f32_16x16x32_bf16(afr[k0], b2, acc[2], 0, 0, 0);
                    acc[3] = __builtin_amdgcn_mfma_f32_16x16x32_bf16(afr[k0], b3, acc[3], 0, 0, 0);
                }
                __builtin_amdgcn_s_setprio(0);
            }
            // producer for chunk ci+1 certifies its DMA before the barrier that gates it
            if (ci < 7 && prod == ((ci + 1) & 3)) asm volatile("s_waitcnt vmcnt(0)" ::: "memory");
            asm volatile("s_waitcnt lgkmcnt(0)" ::: "memory");
            __builtin_amdgcn_s_barrier();   // end-bar(ci): buf reads done; buf[ci+1] ready
            __builtin_amdgcn_sched_barrier(0);
            // issue DMA for chunk ci+2 into the buffer just freed
            if (prod == ((ci + 2) & 3)) {
                int g = t * 8 + ci + 2;
                if (g < 8 * T_) ISSUE((ci + 2) & 7, buf);
            }
            // epilogue
            if (isComp) {
                const int np = ci * 128 + c2 * 64 + fr;
                const int u = (2 * ci + c2) * 16 + fr;
                float bfv[4], wxv[4][4];
                #pragma unroll
                for (int g = 0; g < 4; ++g) bfv[g] = bfL[np + g * 16];
                #pragma unroll
                for (int k = 0; k < 4; ++k)
                    #pragma unroll
                    for (int g = 0; g < 4; ++g)
                        wxv[k][g] = bf2f(wxL[k * 1024 + np + g * 16]);
                #pragma unroll
                for (int rr = 0; rr < 4; ++rr) {
                    float xk[4] = {xv[rr].x, xv[rr].y, xv[rr].z, xv[rr].w};
                    float g0 = acc[0][rr] + bfv[0];
                    float g1 = acc[1][rr] + bfv[1];
                    float g2 = acc[2][rr] + bfv[2];
                    float g3 = acc[3][rr] + bfv[3];
                    #pragma unroll
                    for (int k = 0; k < 4; ++k) {
                        g0 = fmaf(xk[k], wxv[k][0], g0);
                        g1 = fmaf(xk[k], wxv[k][1], g1);
                        g2 = fmaf(xk[k], wxv[k][2], g2);
                        g3 = fmaf(xk[k], wxv[k][3], g3);
                    }
                    float iv = fast_sigmoid(g0);
                    float fv = fast_sigmoid(g1);
                    float gv = fast_tanh(g2);
                    float ov = fast_sigmoid(g3);
                    float cn = fv * cReg[ci * 4 + rr] + iv * gv;
                    cReg[ci * 4 + rr] = cn;
                    float hval = ov * fast_tanh(cn);
                    if (DEC) hC[ci * 4 + rr] = hval;
                    hL[(rh * 16 + kg * 4 + rr) * 264 + u] = f2bf(hval);
                }
            }
        }

        if (DEC) {
            // ctrl head: per-lane partials over this wave's 8 units, reduce over fr then c2
            if (isComp) {
                float p0[4] = {0.f, 0.f, 0.f, 0.f}, p1[4] = {0.f, 0.f, 0.f, 0.f};
                #pragma unroll
                for (int ci = 0; ci < 8; ++ci) {
                    float w0 = wcReg[ci * 2], w1 = wcReg[ci * 2 + 1];
                    #pragma unroll
                    for (int rr = 0; rr < 4; ++rr) {
                        p0[rr] = fmaf(hC[ci * 4 + rr], w0, p0[rr]);
                        p1[rr] = fmaf(hC[ci * 4 + rr], w1, p1[rr]);
                    }
                }
                #pragma unroll
                for (int m = 1; m < 16; m <<= 1) {
                    #pragma unroll
                    for (int rr = 0; rr < 4; ++rr) {
                        p0[rr] += __shfl_xor(p0[rr], m);
                        p1[rr] += __shfl_xor(p1[rr], m);
                    }
                }
                if (fr == 0) {
                    #pragma unroll
                    for (int rr = 0; rr < 4; ++rr) {
                        int row = rh * 16 + kg * 4 + rr;
                        redL[row * 4 + c2 * 2 + 0] = p0[rr];
                        redL[row * 4 + c2 * 2 + 1] = p1[rr];
                    }
                }
            }
            asm volatile("s_waitcnt lgkmcnt(0)" ::: "memory");
            __builtin_amdgcn_s_barrier();   // B_ctrl
            if (tid < RB) {
                float pedal = redL[tid * 4 + 0] + redL[tid * 4 + 2] + bc0;
                float steer = fminf(fmaxf(redL[tid * 4 + 1] + redL[tid * 4 + 3] + bc1, -0.5f), 0.5f);
                float4 sv = *(float4*)(sLp + tid * 4);
                float v = sv.w;
                float v1 = fminf(fmaxf(v + pedal * DT_, 0.f), 10.f);
                float pd = fminf(fmaxf(v * tanf(steer) * (1.f / 2.5f), -1.57f), 1.57f);
                float4 ns;
                ns.x = sv.x + v1 * cosf(sv.z) * DT_;
                ns.y = sv.y + v1 * sinf(sv.z) * DT_;
                ns.z = sv.z + pd * DT_;
                ns.w = v1;
                *(float4*)(sLp + tid * 4) = ns;
                *(float4*)(recons + ((size_t)(rowBase + tid) * T_ + t) * 4) = ns;
            }
        }
    }

    if (!DEC) {
        asm volatile("s_waitcnt lgkmcnt(0)" ::: "memory");
        __builtin_amdgcn_s_barrier();
        #pragma unroll
        for (int w = 0; w < 2; ++w) {
            int cid = tid + w * 512;
            int row = cid >> 5, seg = cid & 31;
            *(short8*)(hOut + (size_t)(rowBase + row) * 256 + seg * 8) =
                *(const short8*)(hL + row * 264 + seg * 8);
        }
    }
    #undef ISSUE
}

// ---------- MFMA GEMM for MLP layers (z-batched) ----------
__global__ __launch_bounds__(256) void mlp_gemm_kernel(
    const unsigned short* __restrict__ Ain, size_t aZStride,
    const unsigned short* __restrict__ WTb, size_t wZStride,
    const float* __restrict__ b0, const float* __restrict__ b1,
    float* __restrict__ outF, size_t ofZStride,
    unsigned short* __restrict__ outB, size_t obZStride,
    int act)
{
    const int z = blockIdx.z;
    const unsigned short* A  = Ain + (size_t)z * aZStride;
    const unsigned short* WT = WTb + (size_t)z * wZStride;
    const float* bias = z ? b1 : b0;

    __shared__ __align__(16) short sA[64 * 256];
    __shared__ __align__(16) short sBm[64 * 256];
    const int tid = threadIdx.x;
    const int lane = tid & 63;
    const int wr = (tid >> 7) & 1;
    const int wc = (tid >> 6) & 1;
    const int rowBase = blockIdx.x * 64;
    const int nBase = blockIdx.y * 64;

    {
        const unsigned short* gA = A + (size_t)rowBase * 256;
        const unsigned short* gB = WT + (size_t)nBase * 256;
        #pragma unroll
        for (int i = 0; i < 8; ++i) {
            int ch = tid + i * 256;
            int row = ch >> 5, slot = ch & 31;
            float4 va = *(const float4*)(gA + row * 256 + slot * 8);
            float4 vb = *(const float4*)(gB + row * 256 + slot * 8);
            int sl = slot ^ (row & 7);
            *(float4*)(sA + row * 256 + sl * 8) = va;
            *(float4*)(sBm + row * 256 + sl * 8) = vb;
        }
    }
    __syncthreads();

    const int fr = lane & 15;
    const int kg = lane >> 4;
    f32x4 acc[2][2] = {};
    #pragma unroll
    for (int k0 = 0; k0 < 8; ++k0) {
        int kch = k0 * 4 + kg;
        short8 a[2], b[2];
        #pragma unroll
        for (int m = 0; m < 2; ++m) {
            int r = wr * 32 + m * 16 + fr;
            a[m] = *(const short8*)(sA + r * 256 + (kch ^ (r & 7)) * 8);
        }
        #pragma unroll
        for (int n = 0; n < 2; ++n) {
            int r = wc * 32 + n * 16 + fr;
            b[n] = *(const short8*)(sBm + r * 256 + (kch ^ (r & 7)) * 8);
        }
        #pragma unroll
        for (int m = 0; m < 2; ++m)
            #pragma unroll
            for (int n = 0; n < 2; ++n)
                acc[m][n] = __builtin_amdgcn_mfma_f32_16x16x32_bf16(a[m], b[n], acc[m][n], 0, 0, 0);
    }

    #pragma unroll
    for (int m = 0; m < 2; ++m) {
        #pragma unroll
        for (int n = 0; n < 2; ++n) {
            int col = nBase + wc * 32 + n * 16 + fr;
            float bv = bias[col];
            #pragma unroll
            for (int r = 0; r < 4; ++r) {
                int row = rowBase + wr * 32 + m * 16 + kg * 4 + r;
                float v = acc[m][n][r] + bv;
                if (act) v = v > 0.f ? v : 0.01f * v;
                if (outF) outF[(size_t)z * ofZStride + (size_t)row * H_ + col] = v;
                if (outB) outB[(size_t)z * obZStride + (size_t)row * H_ + col] = f2bf(v);
            }
        }
    }
}

// ---------- z = tanh(eps*exp(0.5*lv)+mu) -> bf16 ----------
__global__ void z_kernel(const float* __restrict__ eps, const float* __restrict__ mu,
                         const float* __restrict__ lv, unsigned short* __restrict__ z) {
    int id = blockIdx.x * blockDim.x + threadIdx.x;
    z[id] = f2bf(tanhf(eps[id] * expf(0.5f * lv[id]) + mu[id]));
}

extern "C" void kernel_launch(void* const* d_in, const int* in_sizes, int n_in,
                              void* d_out, int out_size, void* d_ws, size_t ws_size,
                              hipStream_t stream) {
    (void)in_sizes; (void)n_in; (void)out_size; (void)ws_size;
    const float* traj       = (const float*)d_in[0];
    const float* init_s     = (const float*)d_in[1];
    const float* eps        = (const float*)d_in[2];
    const float* enc_emb_W  = (const float*)d_in[3];
    const float* enc_emb_b  = (const float*)d_in[4];
    const float* enc_Wih    = (const float*)d_in[5];
    const float* enc_bih    = (const float*)d_in[6];
    const float* enc_Whh    = (const float*)d_in[7];
    const float* enc_bhh    = (const float*)d_in[8];
    const float* mu_W       = (const float*)d_in[9];
    const float* mu_b       = (const float*)d_in[10];
    const float* lv_W       = (const float*)d_in[11];
    const float* lv_b       = (const float*)d_in[12];
    const float* dec_emb_W  = (const float*)d_in[13];
    const float* dec_emb_b  = (const float*)d_in[14];
    const float* dec_init_W = (const float*)d_in[15];
    const float* dec_init_b = (const float*)d_in[16];
    const float* dec_Wih    = (const float*)d_in[17];
    const float* dec_bih    = (const float*)d_in[18];
    const float* dec_Whh    = (const float*)d_in[19];
    const float* dec_bhh    = (const float*)d_in[20];
    const float* ctrl_W     = (const float*)d_in[21];
    const float* ctrl_b     = (const float*)d_in[22];

    float* out = (float*)d_out;
    float* recons = out;                              // B*T*4
    float* expert = out + (size_t)B_ * T_ * 4;        // B*T*4
    float* mu_out = expert + (size_t)B_ * T_ * 4;     // B*H
    float* lv_out = mu_out + (size_t)B_ * H_;         // B*H

    float* ws = (float*)d_ws;
    size_t o = 0;
    float* rel = ws + o;  o += (size_t)B_ * T_ * 4;
    unsigned short* WhPE = (unsigned short*)(ws + o); o += NG_ * H_ / 2;
    unsigned short* WhPD = (unsigned short*)(ws + o); o += NG_ * H_ / 2;
    unsigned short* WT9  = (unsigned short*)(ws + o); o += 9 * H_ * H_ / 2;
    float* WxPE = ws + o; o += 4 * NG_;
    float* WxPD = ws + o; o += 4 * NG_;
    float* bfPE = ws + o; o += NG_;
    float* bfPD = ws + o; o += NG_;
    unsigned short* hEnc = (unsigned short*)(ws + o); o += (size_t)B_ * H_ / 2;
    unsigned short* tbA  = (unsigned short*)(ws + o); o += (size_t)B_ * H_;  // 2 z-slots
    unsigned short* tbB  = (unsigned short*)(ws + o); o += (size_t)B_ * H_;  // 2 z-slots
    float* cInit = ws + o; o += (size_t)B_ * H_;
    unsigned short* hInit = (unsigned short*)(ws + o); o += (size_t)B_ * H_ / 2;

    hipFuncSetAttribute((const void*)lstm_persist4_kernel<0>,
                        hipFuncAttributeMaxDynamicSharedMemorySize, SMEM4);
    hipFuncSetAttribute((const void*)lstm_persist4_kernel<1>,
                        hipFuncAttributeMaxDynamicSharedMemorySize, SMEM4);

    // ---- prep ----
    fold_perm_kernel<<<80, 256, 0, stream>>>(enc_emb_W, enc_emb_b, enc_Wih, enc_bih, enc_bhh, WxPE, bfPE);
    fold_perm_kernel<<<80, 256, 0, stream>>>(dec_emb_W, dec_emb_b, dec_Wih, dec_bih, dec_bhh, WxPD, bfPD);
    prep_whp_kernel<<<1024, 256, 0, stream>>>(enc_Whh, WhPE);
    prep_whp_kernel<<<1024, 256, 0, stream>>>(dec_Whh, WhPD);
    prep_wt_all_kernel<<<dim3(256, 9), 256, 0, stream>>>(mu_W, lv_W, dec_init_W, WT9);
    rel_kernel<<<(B_ * T_ + 255) / 256, 256, 0, stream>>>(traj, rel, (float4*)expert);

    // ---- encoder (one persistent launch) ----
    lstm_persist4_kernel<0><<<NBLK, 512, SMEM4, stream>>>(
        rel, WhPE, WxPE, bfPE, nullptr, nullptr, nullptr, nullptr, nullptr, hEnc, nullptr);

    // ---- mu/lv MLPs, z-batched ----
    dim3 gridM2(B_ / 64, H_ / 64, 2);
    size_t BH = (size_t)B_ * H_;
    mlp_gemm_kernel<<<gridM2, 256, 0, stream>>>(hEnc, 0, WT9 + 0 * 65536, (size_t)4 * 65536,
                                                mu_b + 0,   lv_b + 0,   nullptr, 0, tbA, BH, 1);
    mlp_gemm_kernel<<<gridM2, 256, 0, stream>>>(tbA, BH, WT9 + 1 * 65536, (size_t)4 * 65536,
                                                mu_b + 256, lv_b + 256, nullptr, 0, tbB, BH, 1);
    mlp_gemm_kernel<<<gridM2, 256, 0, stream>>>(tbB, BH, WT9 + 2 * 65536, (size_t)4 * 65536,
                                                mu_b + 512, lv_b + 512, nullptr, 0, tbA, BH, 1);
    mlp_gemm_kernel<<<gridM2, 256, 0, stream>>>(tbA, BH, WT9 + 3 * 65536, (size_t)4 * 65536,
                                                mu_b + 768, lv_b + 768, mu_out, BH, nullptr, 0, 1);

    // ---- z, decoder init ----
    z_kernel<<<B_ * H_ / 256, 256, 0, stream>>>(eps, mu_out, lv_out, tbB);
    dim3 gridM1(B_ / 64, H_ / 64, 1);
    mlp_gemm_kernel<<<gridM1, 256, 0, stream>>>(tbB, 0, WT9 + 8 * 65536, 0,
                                                dec_init_b, dec_init_b, cInit, 0, hInit, 0, 0);

    // ---- decoder (one persistent launch) ----
    lstm_persist4_kernel<1><<<NBLK, 512, SMEM4, stream>>>(
        nullptr, WhPD, WxPD, bfPD, cInit, hInit, init_s, ctrl_W, ctrl_b, nullptr, recons);
}

// Round 7
// 1223.496 us; speedup vs baseline: 2.3820x; 2.3820x over previous
//
#include <hip/hip_runtime.h>
#include <math.h>

#define B_ 8192
#define T_ 30
#define H_ 256
#define NG_ 1024
#define DT_ 0.03f
#define RB 32
#define NBLK (B_ / RB)   // 256
#define WREP 8           // weight replicas (one per XCD)

typedef __attribute__((ext_vector_type(8))) short short8;
typedef __attribute__((ext_vector_type(4))) float f32x4;

__device__ inline float bf2f(unsigned short u) {
    unsigned int x = ((unsigned int)u) << 16;
    return __builtin_bit_cast(float, x);
}
__device__ inline unsigned short f2bf(float f) {
    unsigned int x = __builtin_bit_cast(unsigned int, f);
    return (unsigned short)((x + 0x7FFF + ((x >> 16) & 1)) >> 16);
}
__device__ inline float fast_tanh(float x) {
    float e = __expf(2.f * x);
    return 1.f - 2.f / (e + 1.f);
}
__device__ inline float fast_sigmoid(float x) {
    return 1.f / (1.f + __expf(-x));
}

// ---------- fused fold+permute: WxP[r][n'] = (W1@W2)[r][co(n')], bfP[n'] = (b1@W2+bih+bhh)[co] ----------
// n' = bN*64 + g*16 + j  <->  co = g*256 + bN*16 + j
__global__ void fold_perm_kernel(const float* __restrict__ W1, const float* __restrict__ b1,
                                 const float* __restrict__ W2,
                                 const float* __restrict__ bih, const float* __restrict__ bhh,
                                 float* __restrict__ WxP, float* __restrict__ bfP) {
    __shared__ float sP[4][64];
    const int t63 = threadIdx.x & 63;
    const int kc = threadIdx.x >> 6;
    int o = blockIdx.x * 64 + t63;          // 0..5119 (r=4 is bias row)
    int r = o >> 10;
    int np = o & 1023;
    int bN = np >> 6, g = (np >> 4) & 3, j = np & 15;
    int co = g * 256 + bN * 16 + j;
    const float* w1row = (r < 4) ? (W1 + r * 128) : b1;
    float acc = 0.f;
    #pragma unroll 8
    for (int k = kc * 32; k < kc * 32 + 32; ++k)
        acc = fmaf(w1row[k], W2[k * NG_ + co], acc);
    sP[kc][t63] = acc;
    __syncthreads();
    if (kc == 0) {
        acc = sP[0][t63] + sP[1][t63] + sP[2][t63] + sP[3][t63];
        if (r < 4) WxP[r * NG_ + np] = acc;
        else       bfP[np] = acc + bih[co] + bhh[co];
    }
}

// Packed B for direct L2->VGPR fragment loads, replicated WREP times (one image per XCD):
// Wpk[rep][ colgrp*4096 + k0*512 + kg*128 + fr*8 + e ] = bf16( Whh[k0*32+kg*8+e][ co(colgrp*16+fr) ] )
__global__ void prep_pack_kernel(const float* __restrict__ W, unsigned short* __restrict__ Wpk) {
    int id = blockIdx.x * blockDim.x + threadIdx.x;  // 1024*256
    int rep = blockIdx.y;
    int np = id >> 8, k = id & 255;
    int bN = np >> 6, g = (np >> 4) & 3, j = np & 15;
    int co = g * 256 + bN * 16 + j;
    int colgrp = np >> 4, fr = np & 15;
    int k0 = k >> 5, kg = (k >> 3) & 3, e = k & 7;
    Wpk[(size_t)rep * (NG_ * H_) + colgrp * 4096 + k0 * 512 + kg * 128 + fr * 8 + e] =
        f2bf(W[(size_t)k * NG_ + co]);
}

// WT[m][n][k] = bf16(W_m[k][n]) for 9 matrices (mu0..3, lv0..3, dec_init)
__global__ void prep_wt_all_kernel(const float* __restrict__ muW, const float* __restrict__ lvW,
                                   const float* __restrict__ diW, unsigned short* __restrict__ WT9) {
    int m = blockIdx.y;
    const float* src = (m < 4) ? muW + (size_t)m * 65536
                     : (m < 8) ? lvW + (size_t)(m - 4) * 65536
                               : diW;
    int id = blockIdx.x * 256 + threadIdx.x;
    int n = id >> 8, k = id & 255;
    WT9[(size_t)m * 65536 + id] = f2bf(src[k * H_ + n]);
}

// ---------- rel input + expert passthrough ----------
__global__ void rel_kernel(const float* __restrict__ traj, float* __restrict__ rel,
                           float4* __restrict__ expert) {
    int id = blockIdx.x * blockDim.x + threadIdx.x;
    if (id >= B_ * T_) return;
    int t = id % T_;
    const float* p = traj + (size_t)id * 4;
    float x = p[0], y = p[1];
    if (t > 0) { x -= p[-4]; y -= p[-3]; }
    float* o = rel + (size_t)id * 4;
    o[0] = x; o[1] = y; o[2] = p[2]; o[3] = p[3];
    expert[id] = ((const float4*)traj)[id];
}

// ---------- persistent LSTM v3r: 8 waves, B direct from L2 (per-XCD replica), 1-2 barriers/step ----------
template <int DEC>
__global__ __launch_bounds__(512, 2) void lstm_persist5_kernel(
    const float* __restrict__ rel,            // enc: [B][T][4]
    const unsigned short* __restrict__ Wpk,   // packed weights x WREP replicas
    const float* __restrict__ WxP,            // [4][1024] permuted
    const float* __restrict__ bfP,            // [1024] permuted
    const float* __restrict__ cInit,          // dec: [B][256] f32
    const unsigned short* __restrict__ hInit, // dec: [B][256] bf16
    const float* __restrict__ initS,          // dec: [B][4]
    const float* __restrict__ Wc,             // dec: [256][2]
    const float* __restrict__ bc,             // dec: [2]
    unsigned short* __restrict__ hOut,        // enc: [B][256] bf16
    float* __restrict__ recons)               // dec: [B][T][4]
{
    __shared__ __align__(16) unsigned short hBuf[2][32 * 264];  // h ping-pong, unit-indexed
    __shared__ float wxL[4 * 1024];
    __shared__ float bfL[1024];
    __shared__ float WcL[512];
    __shared__ float sL[RB * 4];
    __shared__ float redL[RB * 8 * 2];

    const int tid = threadIdx.x;
    const int lane = tid & 63;
    const int fr = lane & 15;
    const int kg = lane >> 4;
    const int cg = tid >> 6;          // wave 0..7: owns cols [cg*128, cg*128+128)
    const int rowBase = blockIdx.x * RB;

    // select this XCD's private weight replica (L2 locality)
    int xcc;
    asm volatile("s_getreg_b32 %0, hwreg(HW_REG_XCC_ID)" : "=s"(xcc));
    const unsigned short* Wrep = Wpk + (size_t)(xcc & (WREP - 1)) * (NG_ * H_);

    // ---- prologue ----
    #pragma unroll
    for (int w = 0; w < 2; ++w) {
        int cid = tid + w * 512;                  // 1024 chunks of 8 shorts
        int row = cid >> 5, seg = cid & 31;
        if (DEC) *(short8*)(&hBuf[0][row * 264 + seg * 8]) =
                     *(const short8*)(hInit + (size_t)(rowBase + row) * 256 + seg * 8);
        else {
            short8 z = {0, 0, 0, 0, 0, 0, 0, 0};
            *(short8*)(&hBuf[0][row * 264 + seg * 8]) = z;
        }
    }
    #pragma unroll
    for (int w = 0; w < 8; ++w) wxL[tid + w * 512] = WxP[tid + w * 512];
    #pragma unroll
    for (int w = 0; w < 2; ++w) bfL[tid + w * 512] = bfP[tid + w * 512];
    if (DEC) {
        if (tid < 128) *(float4*)(WcL + tid * 4) = *(const float4*)(Wc + tid * 4);
        if (tid < RB)  *(float4*)(sL + tid * 4) = *(const float4*)(initS + (size_t)(rowBase + tid) * 4);
    }
    float bc0 = 0.f, bc1 = 0.f;
    if (DEC && tid < RB) { bc0 = bc[0]; bc1 = bc[1]; }

    // c in registers: [sc][m][rr] ; unit u = (cg*2+sc)*16+fr, row = m*16+kg*4+rr
    float cReg[16];
    #pragma unroll
    for (int sc = 0; sc < 2; ++sc)
        #pragma unroll
        for (int m = 0; m < 2; ++m)
            #pragma unroll
            for (int rr = 0; rr < 4; ++rr) {
                if (DEC) cReg[sc * 8 + m * 4 + rr] =
                    cInit[(size_t)(rowBase + m * 16 + kg * 4 + rr) * 256 + (cg * 2 + sc) * 16 + fr];
                else cReg[sc * 8 + m * 4 + rr] = 0.f;
            }
    float hC[16];

    __syncthreads();

    for (int t = 0; t < T_; ++t) {
        const unsigned short* rbuf = hBuf[t & 1];
        unsigned short* wbuf = hBuf[(t + 1) & 1];

        // A-fragments: rows m*16+fr, k-chunk kg (all 256 k)
        short8 afr[2][8];
        #pragma unroll
        for (int m = 0; m < 2; ++m)
            #pragma unroll
            for (int k0 = 0; k0 < 8; ++k0)
                afr[m][k0] = *(const short8*)(rbuf + (m * 16 + fr) * 264 + (k0 * 4 + kg) * 8);

        // x vectors for epilogue (same for both sc halves; loaded once per step)
        float4 xv[2][4];
        #pragma unroll
        for (int m = 0; m < 2; ++m)
            #pragma unroll
            for (int rr = 0; rr < 4; ++rr) {
                int row = m * 16 + kg * 4 + rr;
                if (DEC) xv[m][rr] = *(const float4*)(sL + row * 4);
                else     xv[m][rr] = *(const float4*)(rel + ((size_t)(rowBase + row) * T_ + t) * 4);
            }

        #pragma unroll
        for (int sc = 0; sc < 2; ++sc) {
            const unsigned short* wbase = Wrep + (size_t)(cg * 2 + sc) * 4 * 4096 + lane * 8;
            // 4-deep k0 prefetch rotation
            short8 bq[4][4];
            #pragma unroll
            for (int p = 0; p < 4; ++p)
                #pragma unroll
                for (int n = 0; n < 4; ++n)
                    bq[p][n] = *(const short8*)(wbase + n * 4096 + p * 512);

            f32x4 acc[2][4] = {};
            #pragma unroll
            for (int k0 = 0; k0 < 8; ++k0) {
                #pragma unroll
                for (int m = 0; m < 2; ++m)
                    #pragma unroll
                    for (int n = 0; n < 4; ++n)
                        acc[m][n] = __builtin_amdgcn_mfma_f32_16x16x32_bf16(
                            afr[m][k0], bq[k0 & 3][n], acc[m][n], 0, 0, 0);
                if (k0 + 4 < 8) {
                    #pragma unroll
                    for (int n = 0; n < 4; ++n)
                        bq[k0 & 3][n] = *(const short8*)(wbase + n * 4096 + (k0 + 4) * 512);
                }
            }

            // epilogue: unit u = (cg*2+sc)*16+fr, gate g = acc[m][g]
            const int bn = cg * 2 + sc;
            const int np0 = bn * 64 + fr;
            const int u = bn * 16 + fr;
            float bfv[4], wxv[4][4];
            #pragma unroll
            for (int g = 0; g < 4; ++g) bfv[g] = bfL[np0 + g * 16];
            #pragma unroll
            for (int k = 0; k < 4; ++k)
                #pragma unroll
                for (int g = 0; g < 4; ++g)
                    wxv[k][g] = wxL[k * 1024 + np0 + g * 16];
            #pragma unroll
            for (int m = 0; m < 2; ++m) {
                #pragma unroll
                for (int rr = 0; rr < 4; ++rr) {
                    int row = m * 16 + kg * 4 + rr;
                    float xk[4] = {xv[m][rr].x, xv[m][rr].y, xv[m][rr].z, xv[m][rr].w};
                    float g0 = acc[m][0][rr] + bfv[0];
                    float g1 = acc[m][1][rr] + bfv[1];
                    float g2 = acc[m][2][rr] + bfv[2];
                    float g3 = acc[m][3][rr] + bfv[3];
                    #pragma unroll
                    for (int k = 0; k < 4; ++k) {
                        g0 = fmaf(xk[k], wxv[k][0], g0);
                        g1 = fmaf(xk[k], wxv[k][1], g1);
                        g2 = fmaf(xk[k], wxv[k][2], g2);
                        g3 = fmaf(xk[k], wxv[k][3], g3);
                    }
                    float iv = fast_sigmoid(g0);
                    float fv = fast_sigmoid(g1);
                    float gv = fast_tanh(g2);
                    float ov = fast_sigmoid(g3);
                    int ci = sc * 8 + m * 4 + rr;
                    float cn = fv * cReg[ci] + iv * gv;
                    cReg[ci] = cn;
                    float hval = ov * fast_tanh(cn);
                    if (DEC) hC[ci] = hval;
                    wbuf[row * 264 + u] = f2bf(hval);
                }
            }
        }

        if (DEC) {
            // ctrl head partials: per lane, 8 rows x 2 units
            float p0[8], p1[8];
            #pragma unroll
            for (int i = 0; i < 8; ++i) { p0[i] = 0.f; p1[i] = 0.f; }
            #pragma unroll
            for (int sc = 0; sc < 2; ++sc) {
                int u = (cg * 2 + sc) * 16 + fr;
                float w0 = WcL[u * 2], w1 = WcL[u * 2 + 1];
                #pragma unroll
                for (int m = 0; m < 2; ++m)
                    #pragma unroll
                    for (int rr = 0; rr < 4; ++rr) {
                        p0[m * 4 + rr] = fmaf(hC[sc * 8 + m * 4 + rr], w0, p0[m * 4 + rr]);
                        p1[m * 4 + rr] = fmaf(hC[sc * 8 + m * 4 + rr], w1, p1[m * 4 + rr]);
                    }
            }
            #pragma unroll
            for (int msk = 1; msk < 16; msk <<= 1)
                #pragma unroll
                for (int i = 0; i < 8; ++i) {
                    p0[i] += __shfl_xor(p0[i], msk);
                    p1[i] += __shfl_xor(p1[i], msk);
                }
            if (fr == 0) {
                #pragma unroll
                for (int m = 0; m < 2; ++m)
                    #pragma unroll
                    for (int rr = 0; rr < 4; ++rr) {
                        int row = m * 16 + kg * 4 + rr;
                        redL[(row * 8 + cg) * 2 + 0] = p0[m * 4 + rr];
                        redL[(row * 8 + cg) * 2 + 1] = p1[m * 4 + rr];
                    }
            }
            __syncthreads();
            if (tid < RB) {
                float q0 = 0.f, q1 = 0.f;
                #pragma unroll
                for (int w = 0; w < 8; ++w) {
                    q0 += redL[(tid * 8 + w) * 2 + 0];
                    q1 += redL[(tid * 8 + w) * 2 + 1];
                }
                float pedal = q0 + bc0;
                float steer = fminf(fmaxf(q1 + bc1, -0.5f), 0.5f);
                float4 sv = *(float4*)(sL + tid * 4);
                float v = sv.w;
                float v1 = fminf(fmaxf(v + pedal * DT_, 0.f), 10.f);
                float pd = fminf(fmaxf(v * tanf(steer) * (1.f / 2.5f), -1.57f), 1.57f);
                float4 ns;
                ns.x = sv.x + v1 * cosf(sv.z) * DT_;
                ns.y = sv.y + v1 * sinf(sv.z) * DT_;
                ns.z = sv.z + pd * DT_;
                ns.w = v1;
                *(float4*)(sL + tid * 4) = ns;
                *(float4*)(recons + ((size_t)(rowBase + tid) * T_ + t) * 4) = ns;
            }
            __syncthreads();
        } else {
            __syncthreads();
        }
    }

    if (!DEC) {   // final h -> global
        #pragma unroll
        for (int w = 0; w < 2; ++w) {
            int cid = tid + w * 512;
            int row = cid >> 5, seg = cid & 31;
            *(short8*)(hOut + (size_t)(rowBase + row) * 256 + seg * 8) =
                *(const short8*)(&hBuf[T_ & 1][row * 264 + seg * 8]);
        }
    }
}

// ---------- MFMA GEMM for MLP layers (z-batched) ----------
__global__ __launch_bounds__(256) void mlp_gemm_kernel(
    const unsigned short* __restrict__ Ain, size_t aZStride,
    const unsigned short* __restrict__ WTb, size_t wZStride,
    const float* __restrict__ b0, const float* __restrict__ b1,
    float* __restrict__ outF, size_t ofZStride,
    unsigned short* __restrict__ outB, size_t obZStride,
    int act)
{
    const int z = blockIdx.z;
    const unsigned short* A  = Ain + (size_t)z * aZStride;
    const unsigned short* WT = WTb + (size_t)z * wZStride;
    const float* bias = z ? b1 : b0;

    __shared__ __align__(16) short sA[64 * 256];
    __shared__ __align__(16) short sBm[64 * 256];
    const int tid = threadIdx.x;
    const int lane = tid & 63;
    const int wr = (tid >> 7) & 1;
    const int wc = (tid >> 6) & 1;
    const int rowBase = blockIdx.x * 64;
    const int nBase = blockIdx.y * 64;

    {
        const unsigned short* gA = A + (size_t)rowBase * 256;
        const unsigned short* gB = WT + (size_t)nBase * 256;
        #pragma unroll
        for (int i = 0; i < 8; ++i) {
            int ch = tid + i * 256;
            int row = ch >> 5, slot = ch & 31;
            float4 va = *(const float4*)(gA + row * 256 + slot * 8);
            float4 vb = *(const float4*)(gB + row * 256 + slot * 8);
            int sl = slot ^ (row & 7);
            *(float4*)(sA + row * 256 + sl * 8) = va;
            *(float4*)(sBm + row * 256 + sl * 8) = vb;
        }
    }
    __syncthreads();

    const int fr = lane & 15;
    const int kg = lane >> 4;
    f32x4 acc[2][2] = {};
    #pragma unroll
    for (int k0 = 0; k0 < 8; ++k0) {
        int kch = k0 * 4 + kg;
        short8 a[2], b[2];
        #pragma unroll
        for (int m = 0; m < 2; ++m) {
            int r = wr * 32 + m * 16 + fr;
            a[m] = *(const short8*)(sA + r * 256 + (kch ^ (r & 7)) * 8);
        }
        #pragma unroll
        for (int n = 0; n < 2; ++n) {
            int r = wc * 32 + n * 16 + fr;
            b[n] = *(const short8*)(sBm + r * 256 + (kch ^ (r & 7)) * 8);
        }
        #pragma unroll
        for (int m = 0; m < 2; ++m)
            #pragma unroll
            for (int n = 0; n < 2; ++n)
                acc[m][n] = __builtin_amdgcn_mfma_f32_16x16x32_bf16(a[m], b[n], acc[m][n], 0, 0, 0);
    }

    #pragma unroll
    for (int m = 0; m < 2; ++m) {
        #pragma unroll
        for (int n = 0; n < 2; ++n) {
            int col = nBase + wc * 32 + n * 16 + fr;
            float bv = bias[col];
            #pragma unroll
            for (int r = 0; r < 4; ++r) {
                int row = rowBase + wr * 32 + m * 16 + kg * 4 + r;
                float v = acc[m][n][r] + bv;
                if (act) v = v > 0.f ? v : 0.01f * v;
                if (outF) outF[(size_t)z * ofZStride + (size_t)row * H_ + col] = v;
                if (outB) outB[(size_t)z * obZStride + (size_t)row * H_ + col] = f2bf(v);
            }
        }
    }
}

// ---------- z = tanh(eps*exp(0.5*lv)+mu) -> bf16 ----------
__global__ void z_kernel(const float* __restrict__ eps, const float* __restrict__ mu,
                         const float* __restrict__ lv, unsigned short* __restrict__ z) {
    int id = blockIdx.x * blockDim.x + threadIdx.x;
    z[id] = f2bf(tanhf(eps[id] * expf(0.5f * lv[id]) + mu[id]));
}

extern "C" void kernel_launch(void* const* d_in, const int* in_sizes, int n_in,
                              void* d_out, int out_size, void* d_ws, size_t ws_size,
                              hipStream_t stream) {
    (void)in_sizes; (void)n_in; (void)out_size; (void)ws_size;
    const float* traj       = (const float*)d_in[0];
    const float* init_s     = (const float*)d_in[1];
    const float* eps        = (const float*)d_in[2];
    const float* enc_emb_W  = (const float*)d_in[3];
    const float* enc_emb_b  = (const float*)d_in[4];
    const float* enc_Wih    = (const float*)d_in[5];
    const float* enc_bih    = (const float*)d_in[6];
    const float* enc_Whh    = (const float*)d_in[7];
    const float* enc_bhh    = (const float*)d_in[8];
    const float* mu_W       = (const float*)d_in[9];
    const float* mu_b       = (const float*)d_in[10];
    const float* lv_W       = (const float*)d_in[11];
    const float* lv_b       = (const float*)d_in[12];
    const float* dec_emb_W  = (const float*)d_in[13];
    const float* dec_emb_b  = (const float*)d_in[14];
    const float* dec_init_W = (const float*)d_in[15];
    const float* dec_init_b = (const float*)d_in[16];
    const float* dec_Wih    = (const float*)d_in[17];
    const float* dec_bih    = (const float*)d_in[18];
    const float* dec_Whh    = (const float*)d_in[19];
    const float* dec_bhh    = (const float*)d_in[20];
    const float* ctrl_W     = (const float*)d_in[21];
    const float* ctrl_b     = (const float*)d_in[22];

    float* out = (float*)d_out;
    float* recons = out;                              // B*T*4
    float* expert = out + (size_t)B_ * T_ * 4;        // B*T*4
    float* mu_out = expert + (size_t)B_ * T_ * 4;     // B*H
    float* lv_out = mu_out + (size_t)B_ * H_;         // B*H

    float* ws = (float*)d_ws;
    size_t o = 0;
    float* rel = ws + o;  o += (size_t)B_ * T_ * 4;
    unsigned short* WpkE = (unsigned short*)(ws + o); o += (size_t)WREP * NG_ * H_ / 2;
    unsigned short* WpkD = (unsigned short*)(ws + o); o += (size_t)WREP * NG_ * H_ / 2;
    unsigned short* WT9  = (unsigned short*)(ws + o); o += 9 * H_ * H_ / 2;
    float* WxPE = ws + o; o += 4 * NG_;
    float* WxPD = ws + o; o += 4 * NG_;
    float* bfPE = ws + o; o += NG_;
    float* bfPD = ws + o; o += NG_;
    unsigned short* hEnc = (unsigned short*)(ws + o); o += (size_t)B_ * H_ / 2;
    unsigned short* tbA  = (unsigned short*)(ws + o); o += (size_t)B_ * H_;  // 2 z-slots
    unsigned short* tbB  = (unsigned short*)(ws + o); o += (size_t)B_ * H_;  // 2 z-slots
    float* cInit = ws + o; o += (size_t)B_ * H_;
    unsigned short* hInit = tbA;  // tbA is dead after mlp layer 4; reuse for decoder h-init

    // ---- prep ----
    fold_perm_kernel<<<80, 256, 0, stream>>>(enc_emb_W, enc_emb_b, enc_Wih, enc_bih, enc_bhh, WxPE, bfPE);
    fold_perm_kernel<<<80, 256, 0, stream>>>(dec_emb_W, dec_emb_b, dec_Wih, dec_bih, dec_bhh, WxPD, bfPD);
    prep_pack_kernel<<<dim3(1024, WREP), 256, 0, stream>>>(enc_Whh, WpkE);
    prep_pack_kernel<<<dim3(1024, WREP), 256, 0, stream>>>(dec_Whh, WpkD);
    prep_wt_all_kernel<<<dim3(256, 9), 256, 0, stream>>>(mu_W, lv_W, dec_init_W, WT9);
    rel_kernel<<<(B_ * T_ + 255) / 256, 256, 0, stream>>>(traj, rel, (float4*)expert);

    // ---- encoder (one persistent launch) ----
    lstm_persist5_kernel<0><<<NBLK, 512, 0, stream>>>(
        rel, WpkE, WxPE, bfPE, nullptr, nullptr, nullptr, nullptr, nullptr, hEnc, nullptr);

    // ---- mu/lv MLPs, z-batched ----
    dim3 gridM2(B_ / 64, H_ / 64, 2);
    size_t BH = (size_t)B_ * H_;
    mlp_gemm_kernel<<<gridM2, 256, 0, stream>>>(hEnc, 0, WT9 + 0 * 65536, (size_t)4 * 65536,
                                                mu_b + 0,   lv_b + 0,   nullptr, 0, tbA, BH, 1);
    mlp_gemm_kernel<<<gridM2, 256, 0, stream>>>(tbA, BH, WT9 + 1 * 65536, (size_t)4 * 65536,
                                                mu_b + 256, lv_b + 256, nullptr, 0, tbB, BH, 1);
    mlp_gemm_kernel<<<gridM2, 256, 0, stream>>>(tbB, BH, WT9 + 2 * 65536, (size_t)4 * 65536,
                                                mu_b + 512, lv_b + 512, nullptr, 0, tbA, BH, 1);
    mlp_gemm_kernel<<<gridM2, 256, 0, stream>>>(tbA, BH, WT9 + 3 * 65536, (size_t)4 * 65536,
                                                mu_b + 768, lv_b + 768, mu_out, BH, nullptr, 0, 1);

    // ---- z, decoder init ----
    z_kernel<<<B_ * H_ / 256, 256, 0, stream>>>(eps, mu_out, lv_out, tbB);
    dim3 gridM1(B_ / 64, H_ / 64, 1);
    mlp_gemm_kernel<<<gridM1, 256, 0, stream>>>(tbB, 0, WT9 + 8 * 65536, 0,
                                                dec_init_b, dec_init_b, cInit, 0, hInit, 0, 0);

    // ---- decoder (one persistent launch) ----
    lstm_persist5_kernel<1><<<NBLK, 512, 0, stream>>>(
        nullptr, WpkD, WxPD, bfPD, cInit, hInit, init_s, ctrl_W, ctrl_b, nullptr, recons);
}